// Round 1
// baseline (572.662 us; speedup 1.0000x reference)
//
#include <hip/hip_runtime.h>

typedef __attribute__((ext_vector_type(8))) short bf16x8;
typedef __attribute__((ext_vector_type(4))) float f32x4;

__device__ __forceinline__ short f2bf(float f) {
  unsigned u = __float_as_uint(f);
  return (short)((u + 0x7fffu + ((u >> 16) & 1u)) >> 16);
}
__device__ __forceinline__ float bf2f(short s) {
  return __uint_as_float(((unsigned)(unsigned short)s) << 16);
}

// ---------------------------------------------------------------------------
// K1: full-res conv 192->64 + bias + relu.  x = relu(W0 . [x1;x2] + b0)
// GEMM M=64(out ch) K=192(in ch) N=65536 px per batch, bf16 MFMA, no LDS.
// Each wave: 64 px x 64 out.  b-frags gathered with dword loads (4 segments
// of 64B per inst, fully used), cvt to bf16 in-register.
// ---------------------------------------------------------------------------
__global__ __launch_bounds__(256) void k1_conv192(
    const float* __restrict__ x1, const float* __restrict__ x2,
    const float* __restrict__ w0, const float* __restrict__ b0,
    float* __restrict__ xout)
{
  const int b    = blockIdx.y;
  const int wv   = threadIdx.x >> 6;
  const int lane = threadIdx.x & 63;
  const int quad = lane >> 4;
  const int l16  = lane & 15;
  const int n0   = blockIdx.x * 256 + wv * 64;

  f32x4 acc[4][4];
  #pragma unroll
  for (int mt = 0; mt < 4; ++mt)
    #pragma unroll
    for (int nt = 0; nt < 4; ++nt)
      acc[mt][nt] = (f32x4){0.f, 0.f, 0.f, 0.f};

  #pragma unroll
  for (int kc = 0; kc < 6; ++kc) {
    // A fragments: weights w0[64][192], row-major -> direct per-lane gather
    bf16x8 af[4];
    #pragma unroll
    for (int mt = 0; mt < 4; ++mt) {
      const float* wrow = w0 + (mt * 16 + l16) * 192 + kc * 32 + quad * 8;
      #pragma unroll
      for (int j = 0; j < 8; ++j) af[mt][j] = f2bf(wrow[j]);
    }
    // B fragments: input channels kc*32..+31 (x1 for kc<4 else x2)
    const float* src = (kc < 4)
        ? (x1 + ((long)b * 128 + kc * 32) * 65536)
        : (x2 + ((long)b * 64 + (kc - 4) * 32) * 65536);
    const float* s8 = src + (long)(quad * 8) * 65536;
    bf16x8 bfv[4];
    #pragma unroll
    for (int nt = 0; nt < 4; ++nt) {
      const int p = n0 + nt * 16 + l16;
      #pragma unroll
      for (int j = 0; j < 8; ++j) bfv[nt][j] = f2bf(s8[(long)j * 65536 + p]);
    }
    #pragma unroll
    for (int mt = 0; mt < 4; ++mt)
      #pragma unroll
      for (int nt = 0; nt < 4; ++nt)
        acc[mt][nt] = __builtin_amdgcn_mfma_f32_16x16x32_bf16(
            af[mt], bfv[nt], acc[mt][nt], 0, 0, 0);
  }

  // epilogue: C[row=4*quad+r][col=l16] (m89-verified C/D layout)
  #pragma unroll
  for (int mt = 0; mt < 4; ++mt) {
    #pragma unroll
    for (int r = 0; r < 4; ++r) {
      const int o = mt * 16 + quad * 4 + r;
      const float bias = b0[o];
      float* orow = xout + ((long)b * 64 + o) * 65536;
      #pragma unroll
      for (int nt = 0; nt < 4; ++nt) {
        const int p = n0 + nt * 16 + l16;
        orow[p] = fmaxf(acc[mt][nt][r] + bias, 0.f);
      }
    }
  }
}

// ---------------------------------------------------------------------------
// K2: everything at down4 resolution (1x1 conv commutes with down4).
// Per block: one down-row (64 px), 4 waves; wave g computes out-ch 16g..16g+15.
// Chain: x->x2s->{q,v};  event->e0->ef->{k, ef_cm}.
// ---------------------------------------------------------------------------
__device__ __forceinline__ void conv64(const float (*buf)[65],
                                       const float* __restrict__ w,
                                       const float* __restrict__ bias,
                                       int g, int p, float out[16])
{
  float acc[16];
  #pragma unroll
  for (int j = 0; j < 16; ++j) acc[j] = 0.f;
  #pragma unroll
  for (int c0 = 0; c0 < 64; c0 += 16) {
    float xv[16];
    #pragma unroll
    for (int r = 0; r < 16; ++r) xv[r] = buf[c0 + r][p];
    #pragma unroll
    for (int j = 0; j < 16; ++j) {
      const float* wr = w + (g * 16 + j) * 64 + c0;   // uniform -> s_load
      #pragma unroll
      for (int r = 0; r < 16; ++r) acc[j] += wr[r] * xv[r];
    }
  }
  #pragma unroll
  for (int j = 0; j < 16; ++j) out[j] = fmaxf(acc[j] + bias[g * 16 + j], 0.f);
}

__global__ __launch_bounds__(256) void k2_small(
    const float* __restrict__ xfull, const float* __restrict__ event,
    const float* __restrict__ xw1, const float* __restrict__ xb1,
    const float* __restrict__ ew0, const float* __restrict__ eb0,
    const float* __restrict__ ew1, const float* __restrict__ eb1,
    const float* __restrict__ qw, const float* __restrict__ qb,
    const float* __restrict__ kw, const float* __restrict__ kb,
    const float* __restrict__ vw, const float* __restrict__ vb,
    short* __restrict__ q_pm, short* __restrict__ k_pm,
    short* __restrict__ v_cm, short* __restrict__ ef_cm)
{
  __shared__ float bufA[64][65];
  __shared__ float bufB[64][65];
  const int b  = blockIdx.y;
  const int h4 = blockIdx.x;
  const int t  = threadIdx.x;
  const int p  = t & 63;
  const int g  = __builtin_amdgcn_readfirstlane(t >> 6);
  const int n  = h4 * 64 + p;
  const long fullbase = (long)b * 64 * 65536 + h4 * 1024;

  #pragma unroll
  for (int r = 0; r < 16; ++r) {
    const int ci = g * 16 + r;
    bufA[ci][p] = xfull[fullbase + (long)ci * 65536 + p * 4];
  }
  __syncthreads();
  float s1[16];
  conv64(bufA, xw1, xb1, g, p, s1);
  #pragma unroll
  for (int j = 0; j < 16; ++j) bufB[g * 16 + j][p] = s1[j];
  __syncthreads();
  // overwrite bufA with event at down pixels (all bufA readers done)
  #pragma unroll
  for (int r = 0; r < 16; ++r) {
    const int ci = g * 16 + r;
    bufA[ci][p] = event[fullbase + (long)ci * 65536 + p * 4];
  }
  float qv[16], vv[16];
  conv64(bufB, qw, qb, g, p, qv);
  conv64(bufB, vw, vb, g, p, vv);
  {
    bf16x8 t0, t1;
    #pragma unroll
    for (int j = 0; j < 8; ++j) { t0[j] = f2bf(qv[j]); t1[j] = f2bf(qv[j + 8]); }
    bf16x8* dst = (bf16x8*)(q_pm + ((long)b * 4096 + n) * 64 + g * 16);
    dst[0] = t0; dst[1] = t1;
  }
  #pragma unroll
  for (int j = 0; j < 16; ++j)
    v_cm[((long)b * 64 + g * 16 + j) * 4096 + n] = f2bf(vv[j]);
  __syncthreads();
  float e0[16];
  conv64(bufA, ew0, eb0, g, p, e0);
  #pragma unroll
  for (int j = 0; j < 16; ++j) bufB[g * 16 + j][p] = e0[j];
  __syncthreads();
  float ef[16];
  conv64(bufB, ew1, eb1, g, p, ef);
  #pragma unroll
  for (int j = 0; j < 16; ++j)
    ef_cm[((long)b * 64 + g * 16 + j) * 4096 + n] = f2bf(ef[j]);
  #pragma unroll
  for (int j = 0; j < 16; ++j) bufA[g * 16 + j][p] = ef[j];
  __syncthreads();
  float kv[16];
  conv64(bufA, kw, kb, g, p, kv);
  {
    bf16x8 t0, t1;
    #pragma unroll
    for (int j = 0; j < 8; ++j) { t0[j] = f2bf(kv[j]); t1[j] = f2bf(kv[j + 8]); }
    bf16x8* dst = (bf16x8*)(k_pm + ((long)b * 4096 + n) * 64 + g * 16);
    dst[0] = t0; dst[1] = t1;
  }
}

// ---------------------------------------------------------------------------
// K3: flash attention per batch.  Q-tile 64 (16/wave), K-tiles of 64.
// q_pm/k_pm: [b][n][64] bf16 (A-operand layout), v_cm: [b][c][4096] bf16.
// O_pm: [b][n][64] fp32.
// ---------------------------------------------------------------------------
__global__ __launch_bounds__(256) void k3_attn(
    const short* __restrict__ q_pm, const short* __restrict__ k_pm,
    const short* __restrict__ v_cm, float* __restrict__ O_pm)
{
  __shared__ short K_lds[64][72];     // [key][ch], pad->row 144B (16B-aligned, 2-way banks)
  __shared__ short V_lds[64][72];     // [ch][key]
  __shared__ short P_lds[4][16][72];  // per-wave P, [q][key]
  const int b    = blockIdx.y;
  const int q0   = blockIdx.x * 64;
  const int t    = threadIdx.x;
  const int wv   = __builtin_amdgcn_readfirstlane(t >> 6);
  const int lane = t & 63;
  const int quad = lane >> 4;
  const int l16  = lane & 15;

  bf16x8 qf[2];
  {
    const short* qp = q_pm + ((long)b * 4096 + q0 + wv * 16 + l16) * 64 + quad * 8;
    qf[0] = *(const bf16x8*)(qp);
    qf[1] = *(const bf16x8*)(qp + 32);
  }
  f32x4 oacc[4];
  #pragma unroll
  for (int f = 0; f < 4; ++f) oacc[f] = (f32x4){0, 0, 0, 0};
  float run_m[4] = {-1e30f, -1e30f, -1e30f, -1e30f};
  float run_l[4] = {0, 0, 0, 0};

  const int kr  = t >> 2;   // staging row 0..63
  const int seg = t & 3;
  const short* ksrc = k_pm + (long)b * 4096 * 64;
  const short* vsrc = v_cm + (long)b * 64 * 4096;

  for (int kt = 0; kt < 64; ++kt) {
    const int k0 = kt * 64;
    __syncthreads();
    {
      const short* s = ksrc + (long)(k0 + kr) * 64 + seg * 16;
      *(bf16x8*)&K_lds[kr][seg * 16]     = *(const bf16x8*)(s);
      *(bf16x8*)&K_lds[kr][seg * 16 + 8] = *(const bf16x8*)(s + 8);
      const short* v = vsrc + (long)kr * 4096 + k0 + seg * 16;
      *(bf16x8*)&V_lds[kr][seg * 16]     = *(const bf16x8*)(v);
      *(bf16x8*)&V_lds[kr][seg * 16 + 8] = *(const bf16x8*)(v + 8);
    }
    __syncthreads();

    // S[16q][64key] = Q K^T
    f32x4 s[4];
    #pragma unroll
    for (int f = 0; f < 4; ++f) s[f] = (f32x4){0, 0, 0, 0};
    #pragma unroll
    for (int kc = 0; kc < 2; ++kc) {
      #pragma unroll
      for (int f = 0; f < 4; ++f) {
        bf16x8 bv = *(const bf16x8*)&K_lds[f * 16 + l16][kc * 32 + quad * 8];
        s[f] = __builtin_amdgcn_mfma_f32_16x16x32_bf16(qf[kc], bv, s[f], 0, 0, 0);
      }
    }
    // online softmax (row = 4*quad+r; stats reduced over the 16 lanes of quad)
    float mrow[4], al[4], rs[4];
    #pragma unroll
    for (int r = 0; r < 4; ++r)
      mrow[r] = fmaxf(fmaxf(s[0][r], s[1][r]), fmaxf(s[2][r], s[3][r]));
    #pragma unroll
    for (int d = 1; d <= 8; d <<= 1)
      #pragma unroll
      for (int r = 0; r < 4; ++r)
        mrow[r] = fmaxf(mrow[r], __shfl_xor(mrow[r], d));
    #pragma unroll
    for (int r = 0; r < 4; ++r) {
      const float nm = fmaxf(run_m[r], mrow[r]);
      al[r] = __expf(run_m[r] - nm);
      run_m[r] = nm;
    }
    float pf[4][4];
    #pragma unroll
    for (int f = 0; f < 4; ++f)
      #pragma unroll
      for (int r = 0; r < 4; ++r)
        pf[f][r] = __expf(s[f][r] - run_m[r]);
    #pragma unroll
    for (int r = 0; r < 4; ++r)
      rs[r] = (pf[0][r] + pf[1][r]) + (pf[2][r] + pf[3][r]);
    #pragma unroll
    for (int d = 1; d <= 8; d <<= 1)
      #pragma unroll
      for (int r = 0; r < 4; ++r)
        rs[r] += __shfl_xor(rs[r], d);
    #pragma unroll
    for (int r = 0; r < 4; ++r) run_l[r] = run_l[r] * al[r] + rs[r];
    #pragma unroll
    for (int f = 0; f < 4; ++f)
      #pragma unroll
      for (int r = 0; r < 4; ++r)
        oacc[f][r] *= al[r];
    // P: C-layout -> LDS -> A-layout (per-wave buffer, in-wave lgkmcnt only)
    #pragma unroll
    for (int f = 0; f < 4; ++f)
      #pragma unroll
      for (int r = 0; r < 4; ++r)
        P_lds[wv][quad * 4 + r][f * 16 + l16] = f2bf(pf[f][r]);
    #pragma unroll
    for (int kc = 0; kc < 2; ++kc) {
      bf16x8 ap = *(const bf16x8*)&P_lds[wv][l16][kc * 32 + quad * 8];
      #pragma unroll
      for (int f = 0; f < 4; ++f) {
        bf16x8 bv = *(const bf16x8*)&V_lds[f * 16 + l16][kc * 32 + quad * 8];
        oacc[f] = __builtin_amdgcn_mfma_f32_16x16x32_bf16(ap, bv, oacc[f], 0, 0, 0);
      }
    }
  }
  #pragma unroll
  for (int r = 0; r < 4; ++r) {
    const float inv = 1.f / run_l[r];
    float* orow = O_pm + ((long)b * 4096 + q0 + wv * 16 + quad * 4 + r) * 64;
    #pragma unroll
    for (int f = 0; f < 4; ++f)
      orow[f * 16 + l16] = oacc[f][r] * inv;
  }
}

// ---------------------------------------------------------------------------
// K4: out = x + THITA*gamma*up4(O);  ef_up = up4(ef).  In-place on d_out.
// ---------------------------------------------------------------------------
__global__ __launch_bounds__(256) void k4_final(
    const float* __restrict__ O_pm, const short* __restrict__ ef_cm,
    const float* __restrict__ gamma, float* __restrict__ dout)
{
  const long idx = (long)blockIdx.x * 256 + threadIdx.x;
  const long e4 = idx * 4;
  const int hw = (int)(e4 & 65535);
  const int bc = (int)(e4 >> 16);
  const int h = hw >> 8, w0 = hw & 255;
  const int n = (h >> 2) * 64 + (w0 >> 2);
  const int b = bc >> 6, c = bc & 63;
  const float s = 1e-4f * gamma[0];
  const float ov = s * O_pm[((long)b * 4096 + n) * 64 + c];
  float4 xv = *(float4*)(dout + e4);
  xv.x += ov; xv.y += ov; xv.z += ov; xv.w += ov;
  *(float4*)(dout + e4) = xv;
  const float ef = bf2f(ef_cm[(long)bc * 4096 + n]);
  const float4 ev = make_float4(ef, ef, ef, ef);
  *(float4*)(dout + 16777216 + e4) = ev;
}

extern "C" void kernel_launch(void* const* d_in, const int* in_sizes, int n_in,
                              void* d_out, int out_size, void* d_ws, size_t ws_size,
                              hipStream_t stream)
{
  const float* x1    = (const float*)d_in[0];
  const float* x2    = (const float*)d_in[1];
  const float* event = (const float*)d_in[2];
  const float* xw0   = (const float*)d_in[3];
  const float* xb0   = (const float*)d_in[4];
  const float* xw1   = (const float*)d_in[5];
  const float* xb1   = (const float*)d_in[6];
  const float* ew0   = (const float*)d_in[7];
  const float* eb0   = (const float*)d_in[8];
  const float* ew1   = (const float*)d_in[9];
  const float* eb1   = (const float*)d_in[10];
  const float* qw    = (const float*)d_in[11];
  const float* qb    = (const float*)d_in[12];
  const float* kw    = (const float*)d_in[13];
  const float* kb    = (const float*)d_in[14];
  const float* vw    = (const float*)d_in[15];
  const float* vb    = (const float*)d_in[16];
  const float* gamma = (const float*)d_in[17];
  float* dout = (float*)d_out;

  char* ws = (char*)d_ws;
  short* q_pm  = (short*)(ws);                  // 2 MiB  [4][4096][64] bf16
  short* k_pm  = (short*)(ws + (2u << 20));     // 2 MiB
  short* v_cm  = (short*)(ws + (4u << 20));     // 2 MiB  [4][64][4096] bf16
  short* ef_cm = (short*)(ws + (6u << 20));     // 2 MiB
  float* O_pm  = (float*)(ws + (8u << 20));     // 4 MiB  [4][4096][64] fp32

  k1_conv192<<<dim3(256, 4), 256, 0, stream>>>(x1, x2, xw0, xb0, dout);
  k2_small<<<dim3(64, 4), 256, 0, stream>>>(dout, event, xw1, xb1, ew0, eb0,
                                            ew1, eb1, qw, qb, kw, kb, vw, vb,
                                            q_pm, k_pm, v_cm, ef_cm);
  k3_attn<<<dim3(64, 4), 256, 0, stream>>>(q_pm, k_pm, v_cm, O_pm);
  k4_final<<<16384, 256, 0, stream>>>(O_pm, ef_cm, gamma, dout);
}

// Round 2
// 481.473 us; speedup vs baseline: 1.1894x; 1.1894x over previous
//
#include <hip/hip_runtime.h>

typedef __attribute__((ext_vector_type(8))) short bf16x8;
typedef __attribute__((ext_vector_type(4))) float f32x4;

// pack two fp32 -> two bf16 (round-half-up) in one v_perm_b32
__device__ __forceinline__ unsigned pk2(float f0, float f1) {
  return __builtin_amdgcn_perm(__float_as_uint(f1) + 0x8000u,
                               __float_as_uint(f0) + 0x8000u, 0x07060302u);
}
__device__ __forceinline__ short f2bf_s(float f) {
  return (short)((__float_as_uint(f) + 0x8000u) >> 16);
}
__device__ __forceinline__ float bf2f(short s) {
  return __uint_as_float(((unsigned)(unsigned short)s) << 16);
}

// ---------------------------------------------------------------------------
// K1: full-res conv 192->64 + bias + relu; also emits compact down4 copy
// xds[b][n][64] bf16 (n = (h/4)*64 + w/4) so K2 never gathers strided fp32.
// ---------------------------------------------------------------------------
__global__ __launch_bounds__(256, 3) void k1_conv192(
    const float* __restrict__ x1, const float* __restrict__ x2,
    const float* __restrict__ w0, const float* __restrict__ b0,
    float* __restrict__ xout, short* __restrict__ xds)
{
  const int b    = blockIdx.y;
  const int wv   = threadIdx.x >> 6;
  const int lane = threadIdx.x & 63;
  const int quad = lane >> 4;
  const int l16  = lane & 15;
  const int n0   = blockIdx.x * 256 + wv * 64;   // block = one full-res row

  f32x4 acc[4][4];
  #pragma unroll
  for (int mt = 0; mt < 4; ++mt)
    #pragma unroll
    for (int nt = 0; nt < 4; ++nt)
      acc[mt][nt] = (f32x4){0.f, 0.f, 0.f, 0.f};

  #pragma unroll
  for (int kc = 0; kc < 6; ++kc) {
    bf16x8 af[4];
    #pragma unroll
    for (int mt = 0; mt < 4; ++mt) {
      const float* wrow = w0 + (mt * 16 + l16) * 192 + kc * 32 + quad * 8;
      float4 wa = *(const float4*)wrow;
      float4 wb = *(const float4*)(wrow + 4);
      union { unsigned i[4]; bf16x8 v; } u;
      u.i[0] = pk2(wa.x, wa.y); u.i[1] = pk2(wa.z, wa.w);
      u.i[2] = pk2(wb.x, wb.y); u.i[3] = pk2(wb.z, wb.w);
      af[mt] = u.v;
    }
    const float* src = (kc < 4)
        ? (x1 + ((long)b * 128 + kc * 32) * 65536)
        : (x2 + ((long)b * 64 + (kc - 4) * 32) * 65536);
    const float* s8 = src + (long)(quad * 8) * 65536;
    bf16x8 bfv[4];
    #pragma unroll
    for (int nt = 0; nt < 4; ++nt) {
      const int p = n0 + nt * 16 + l16;
      float e[8];
      #pragma unroll
      for (int j = 0; j < 8; ++j) e[j] = s8[(long)j * 65536 + p];
      union { unsigned i[4]; bf16x8 v; } u;
      #pragma unroll
      for (int j = 0; j < 4; ++j) u.i[j] = pk2(e[2 * j], e[2 * j + 1]);
      bfv[nt] = u.v;
    }
    #pragma unroll
    for (int mt = 0; mt < 4; ++mt)
      #pragma unroll
      for (int nt = 0; nt < 4; ++nt)
        acc[mt][nt] = __builtin_amdgcn_mfma_f32_16x16x32_bf16(
            af[mt], bfv[nt], acc[mt][nt], 0, 0, 0);
  }

  // full-res store: C[row=4*quad+r][col=l16]
  #pragma unroll
  for (int mt = 0; mt < 4; ++mt) {
    const float4 bb = *(const float4*)(b0 + mt * 16 + quad * 4);
    #pragma unroll
    for (int r = 0; r < 4; ++r) {
      const int o = mt * 16 + quad * 4 + r;
      const float bias = (r == 0) ? bb.x : (r == 1) ? bb.y : (r == 2) ? bb.z : bb.w;
      float* orow = xout + ((long)b * 64 + o) * 65536;
      #pragma unroll
      for (int nt = 0; nt < 4; ++nt)
        orow[n0 + nt * 16 + l16] = fmaxf(acc[mt][nt][r] + bias, 0.f);
    }
  }
  // compact down4 store (h = blockIdx.x, w = wv*64 + nt*16 + l16)
  if (((blockIdx.x & 3) == 0) && ((l16 & 3) == 0)) {
    const int nbase = (blockIdx.x >> 2) * 64 + wv * 16 + (l16 >> 2);
    #pragma unroll
    for (int mt = 0; mt < 4; ++mt) {
      const float4 bb = *(const float4*)(b0 + mt * 16 + quad * 4);
      #pragma unroll
      for (int nt = 0; nt < 4; ++nt) {
        const float v0 = fmaxf(acc[mt][nt][0] + bb.x, 0.f);
        const float v1 = fmaxf(acc[mt][nt][1] + bb.y, 0.f);
        const float v2 = fmaxf(acc[mt][nt][2] + bb.z, 0.f);
        const float v3 = fmaxf(acc[mt][nt][3] + bb.w, 0.f);
        union { unsigned i[2]; unsigned long long q; } u;
        u.i[0] = pk2(v0, v1); u.i[1] = pk2(v2, v3);
        const int n = nbase + nt * 4;
        *(unsigned long long*)(xds + ((long)b * 4096 + n) * 64 + mt * 16 + quad * 4) = u.q;
      }
    }
  }
}

// ---------------------------------------------------------------------------
// K2: all down4-res convs as chained 64x64x64 MFMA GEMMs through LDS.
// Buffers in [px][ch] bf16 (B-operand layout). Wave g owns out-ch 16g..16g+15.
// ---------------------------------------------------------------------------
__device__ __forceinline__ void loadw_frag(const float* __restrict__ w,
                                           int row, int quad, bf16x8 wf[2]) {
  #pragma unroll
  for (int kc = 0; kc < 2; ++kc) {
    const float* p = w + row * 64 + kc * 32 + quad * 8;
    float4 a = *(const float4*)p;
    float4 c = *(const float4*)(p + 4);
    union { unsigned i[4]; bf16x8 v; } u;
    u.i[0] = pk2(a.x, a.y); u.i[1] = pk2(a.z, a.w);
    u.i[2] = pk2(c.x, c.y); u.i[3] = pk2(c.z, c.w);
    wf[kc] = u.v;
  }
}

__device__ __forceinline__ void conv_mfma(const short (*src)[72], short (*dst)[72],
                                          const bf16x8* wf,
                                          const float* __restrict__ bias,
                                          int ch0, int l16, int quad) {
  const float4 bv4 = *(const float4*)(bias + ch0);
  #pragma unroll
  for (int nt = 0; nt < 4; ++nt) {
    f32x4 acc = (f32x4){0.f, 0.f, 0.f, 0.f};
    #pragma unroll
    for (int kc = 0; kc < 2; ++kc) {
      bf16x8 bv = *(const bf16x8*)&src[nt * 16 + l16][kc * 32 + quad * 8];
      acc = __builtin_amdgcn_mfma_f32_16x16x32_bf16(wf[kc], bv, acc, 0, 0, 0);
    }
    const float v0 = fmaxf(acc[0] + bv4.x, 0.f);
    const float v1 = fmaxf(acc[1] + bv4.y, 0.f);
    const float v2 = fmaxf(acc[2] + bv4.z, 0.f);
    const float v3 = fmaxf(acc[3] + bv4.w, 0.f);
    union { unsigned i[2]; unsigned long long q; } u;
    u.i[0] = pk2(v0, v1); u.i[1] = pk2(v2, v3);
    *(unsigned long long*)&dst[nt * 16 + l16][ch0] = u.q;
  }
}

__global__ __launch_bounds__(256) void k2_small(
    const short* __restrict__ xds, const float* __restrict__ event,
    const float* __restrict__ xw1, const float* __restrict__ xb1,
    const float* __restrict__ ew0, const float* __restrict__ eb0,
    const float* __restrict__ ew1, const float* __restrict__ eb1,
    const float* __restrict__ qw, const float* __restrict__ qb,
    const float* __restrict__ kw, const float* __restrict__ kb,
    const float* __restrict__ vw, const float* __restrict__ vb,
    short* __restrict__ q_pm, short* __restrict__ k_pm,
    short* __restrict__ v_cm, short* __restrict__ ef_cm)
{
  __shared__ short A[64][72], Bb[64][72], Cb[64][72];
  const int b    = blockIdx.y;
  const int h4   = blockIdx.x;
  const int t    = threadIdx.x;
  const int lane = t & 63;
  const int g    = t >> 6;
  const int quad = lane >> 4;
  const int l16  = lane & 15;
  const int row  = g * 16 + l16;        // weight row this lane gathers
  const int ch0  = g * 16 + quad * 4;   // C-layout ch base this lane writes

  bf16x8 wfx1[2], wfq[2], wfv[2], wfe0[2], wfe1[2], wfk[2];
  loadw_frag(xw1, row, quad, wfx1);
  loadw_frag(qw,  row, quad, wfq);
  loadw_frag(vw,  row, quad, wfv);
  loadw_frag(ew0, row, quad, wfe0);
  loadw_frag(ew1, row, quad, wfe1);
  loadw_frag(kw,  row, quad, wfk);

  const int px  = t >> 2;
  const int seg = t & 3;
  {  // stage A <- xds (compact, coalesced)
    const short* s = xds + ((long)b * 4096 + h4 * 64 + px) * 64 + seg * 16;
    *(bf16x8*)&A[px][seg * 16]     = *(const bf16x8*)s;
    *(bf16x8*)&A[px][seg * 16 + 8] = *(const bf16x8*)(s + 8);
  }
  __syncthreads();
  conv_mfma(A, Bb, wfx1, xb1, ch0, l16, quad);      // Bb = x_2
  __syncthreads();
  conv_mfma(Bb, A,  wfq, qb, ch0, l16, quad);       // A  = q
  conv_mfma(Bb, Cb, wfv, vb, ch0, l16, quad);       // Cb = v
  __syncthreads();
  {  // store q [n][ch], store v transposed [ch][n], stage event -> Bb
    short* qdst = q_pm + ((long)b * 4096 + h4 * 64 + px) * 64 + seg * 16;
    *(bf16x8*)qdst       = *(const bf16x8*)&A[px][seg * 16];
    *(bf16x8*)(qdst + 8) = *(const bf16x8*)&A[px][seg * 16 + 8];
    union { short s[16]; int4 q2[2]; } vv;
    #pragma unroll
    for (int i = 0; i < 16; ++i) vv.s[i] = Cb[seg * 16 + i][px];
    int4* vdst = (int4*)(v_cm + ((long)b * 64 + px) * 4096 + h4 * 64 + seg * 16);
    vdst[0] = vv.q2[0]; vdst[1] = vv.q2[1];
    const int px2 = t & 63, cg = t >> 6;
    const float* ev = event + (long)b * 64 * 65536 + (long)h4 * 1024 + px2 * 4;
    #pragma unroll
    for (int r = 0; r < 16; r += 2) {
      const float e0v = ev[(long)(cg * 16 + r) * 65536];
      const float e1v = ev[(long)(cg * 16 + r + 1) * 65536];
      *(unsigned*)&Bb[px2][cg * 16 + r] = pk2(e0v, e1v);
    }
  }
  __syncthreads();
  conv_mfma(Bb, A,  wfe0, eb0, ch0, l16, quad);     // A  = e0
  __syncthreads();
  conv_mfma(A,  Cb, wfe1, eb1, ch0, l16, quad);     // Cb = ef
  __syncthreads();
  conv_mfma(Cb, Bb, wfk, kb, ch0, l16, quad);       // Bb = k
  {  // store ef transposed [ch][n]
    union { short s[16]; int4 q2[2]; } vv;
    #pragma unroll
    for (int i = 0; i < 16; ++i) vv.s[i] = Cb[seg * 16 + i][px];
    int4* edst = (int4*)(ef_cm + ((long)b * 64 + px) * 4096 + h4 * 64 + seg * 16);
    edst[0] = vv.q2[0]; edst[1] = vv.q2[1];
  }
  __syncthreads();
  {  // store k [n][ch]
    short* kdst = k_pm + ((long)b * 4096 + h4 * 64 + px) * 64 + seg * 16;
    *(bf16x8*)kdst       = *(const bf16x8*)&Bb[px][seg * 16];
    *(bf16x8*)(kdst + 8) = *(const bf16x8*)&Bb[px][seg * 16 + 8];
  }
}

// ---------------------------------------------------------------------------
// K3: flash attention per batch (unchanged structure; O stored bf16)
// ---------------------------------------------------------------------------
__global__ __launch_bounds__(256) void k3_attn(
    const short* __restrict__ q_pm, const short* __restrict__ k_pm,
    const short* __restrict__ v_cm, short* __restrict__ O_pm)
{
  __shared__ short K_lds[64][72];
  __shared__ short V_lds[64][72];
  __shared__ short P_lds[4][16][72];
  const int b    = blockIdx.y;
  const int q0   = blockIdx.x * 64;
  const int t    = threadIdx.x;
  const int wv   = __builtin_amdgcn_readfirstlane(t >> 6);
  const int lane = t & 63;
  const int quad = lane >> 4;
  const int l16  = lane & 15;

  bf16x8 qf[2];
  {
    const short* qp = q_pm + ((long)b * 4096 + q0 + wv * 16 + l16) * 64 + quad * 8;
    qf[0] = *(const bf16x8*)(qp);
    qf[1] = *(const bf16x8*)(qp + 32);
  }
  f32x4 oacc[4];
  #pragma unroll
  for (int f = 0; f < 4; ++f) oacc[f] = (f32x4){0, 0, 0, 0};
  float run_m[4] = {-1e30f, -1e30f, -1e30f, -1e30f};
  float run_l[4] = {0, 0, 0, 0};

  const int kr  = t >> 2;
  const int seg = t & 3;
  const short* ksrc = k_pm + (long)b * 4096 * 64;
  const short* vsrc = v_cm + (long)b * 64 * 4096;

  for (int kt = 0; kt < 64; ++kt) {
    const int k0 = kt * 64;
    __syncthreads();
    {
      const short* s = ksrc + (long)(k0 + kr) * 64 + seg * 16;
      *(bf16x8*)&K_lds[kr][seg * 16]     = *(const bf16x8*)(s);
      *(bf16x8*)&K_lds[kr][seg * 16 + 8] = *(const bf16x8*)(s + 8);
      const short* v = vsrc + (long)kr * 4096 + k0 + seg * 16;
      *(bf16x8*)&V_lds[kr][seg * 16]     = *(const bf16x8*)(v);
      *(bf16x8*)&V_lds[kr][seg * 16 + 8] = *(const bf16x8*)(v + 8);
    }
    __syncthreads();

    f32x4 s[4];
    #pragma unroll
    for (int f = 0; f < 4; ++f) s[f] = (f32x4){0, 0, 0, 0};
    #pragma unroll
    for (int kc = 0; kc < 2; ++kc) {
      #pragma unroll
      for (int f = 0; f < 4; ++f) {
        bf16x8 bv = *(const bf16x8*)&K_lds[f * 16 + l16][kc * 32 + quad * 8];
        s[f] = __builtin_amdgcn_mfma_f32_16x16x32_bf16(qf[kc], bv, s[f], 0, 0, 0);
      }
    }
    float mrow[4], al[4], rs[4];
    #pragma unroll
    for (int r = 0; r < 4; ++r)
      mrow[r] = fmaxf(fmaxf(s[0][r], s[1][r]), fmaxf(s[2][r], s[3][r]));
    #pragma unroll
    for (int d = 1; d <= 8; d <<= 1)
      #pragma unroll
      for (int r = 0; r < 4; ++r)
        mrow[r] = fmaxf(mrow[r], __shfl_xor(mrow[r], d));
    #pragma unroll
    for (int r = 0; r < 4; ++r) {
      const float nm = fmaxf(run_m[r], mrow[r]);
      al[r] = __expf(run_m[r] - nm);
      run_m[r] = nm;
    }
    float pf[4][4];
    #pragma unroll
    for (int f = 0; f < 4; ++f)
      #pragma unroll
      for (int r = 0; r < 4; ++r)
        pf[f][r] = __expf(s[f][r] - run_m[r]);
    #pragma unroll
    for (int r = 0; r < 4; ++r)
      rs[r] = (pf[0][r] + pf[1][r]) + (pf[2][r] + pf[3][r]);
    #pragma unroll
    for (int d = 1; d <= 8; d <<= 1)
      #pragma unroll
      for (int r = 0; r < 4; ++r)
        rs[r] += __shfl_xor(rs[r], d);
    #pragma unroll
    for (int r = 0; r < 4; ++r) run_l[r] = run_l[r] * al[r] + rs[r];
    #pragma unroll
    for (int f = 0; f < 4; ++f)
      #pragma unroll
      for (int r = 0; r < 4; ++r)
        oacc[f][r] *= al[r];
    #pragma unroll
    for (int f = 0; f < 4; ++f)
      #pragma unroll
      for (int r = 0; r < 4; ++r)
        P_lds[wv][quad * 4 + r][f * 16 + l16] = f2bf_s(pf[f][r]);
    #pragma unroll
    for (int kc = 0; kc < 2; ++kc) {
      bf16x8 ap = *(const bf16x8*)&P_lds[wv][l16][kc * 32 + quad * 8];
      #pragma unroll
      for (int f = 0; f < 4; ++f) {
        bf16x8 bv = *(const bf16x8*)&V_lds[f * 16 + l16][kc * 32 + quad * 8];
        oacc[f] = __builtin_amdgcn_mfma_f32_16x16x32_bf16(ap, bv, oacc[f], 0, 0, 0);
      }
    }
  }
  #pragma unroll
  for (int r = 0; r < 4; ++r) {
    const float inv = 1.f / run_l[r];
    short* orow = O_pm + ((long)b * 4096 + q0 + wv * 16 + quad * 4 + r) * 64;
    #pragma unroll
    for (int f = 0; f < 4; ++f)
      orow[f * 16 + l16] = f2bf_s(oacc[f][r] * inv);
  }
}

// ---------------------------------------------------------------------------
// K4: out = x + THITA*gamma*up4(O);  ef_up = up4(ef).
// ---------------------------------------------------------------------------
__global__ __launch_bounds__(256) void k4_final(
    const short* __restrict__ O_pm, const short* __restrict__ ef_cm,
    const float* __restrict__ gamma, float* __restrict__ dout)
{
  const long idx = (long)blockIdx.x * 256 + threadIdx.x;
  const long e4 = idx * 4;
  const int hw = (int)(e4 & 65535);
  const int bc = (int)(e4 >> 16);
  const int h = hw >> 8, w0 = hw & 255;
  const int n = (h >> 2) * 64 + (w0 >> 2);
  const int b = bc >> 6, c = bc & 63;
  const float s = 1e-4f * gamma[0];
  const float ov = s * bf2f(O_pm[((long)b * 4096 + n) * 64 + c]);
  float4 xv = *(float4*)(dout + e4);
  xv.x += ov; xv.y += ov; xv.z += ov; xv.w += ov;
  *(float4*)(dout + e4) = xv;
  const float ef = bf2f(ef_cm[(long)bc * 4096 + n]);
  *(float4*)(dout + 16777216 + e4) = make_float4(ef, ef, ef, ef);
}

extern "C" void kernel_launch(void* const* d_in, const int* in_sizes, int n_in,
                              void* d_out, int out_size, void* d_ws, size_t ws_size,
                              hipStream_t stream)
{
  const float* x1    = (const float*)d_in[0];
  const float* x2    = (const float*)d_in[1];
  const float* event = (const float*)d_in[2];
  const float* xw0   = (const float*)d_in[3];
  const float* xb0   = (const float*)d_in[4];
  const float* xw1   = (const float*)d_in[5];
  const float* xb1   = (const float*)d_in[6];
  const float* ew0   = (const float*)d_in[7];
  const float* eb0   = (const float*)d_in[8];
  const float* ew1   = (const float*)d_in[9];
  const float* eb1   = (const float*)d_in[10];
  const float* qw    = (const float*)d_in[11];
  const float* qb    = (const float*)d_in[12];
  const float* kw    = (const float*)d_in[13];
  const float* kb    = (const float*)d_in[14];
  const float* vw    = (const float*)d_in[15];
  const float* vb    = (const float*)d_in[16];
  const float* gamma = (const float*)d_in[17];
  float* dout = (float*)d_out;

  char* ws = (char*)d_ws;
  short* q_pm  = (short*)(ws);                   // 2 MiB [4][4096][64] bf16
  short* k_pm  = (short*)(ws + (2u << 20));      // 2 MiB
  short* v_cm  = (short*)(ws + (4u << 20));      // 2 MiB [4][64][4096] bf16
  short* ef_cm = (short*)(ws + (6u << 20));      // 2 MiB
  short* O_pm  = (short*)(ws + (8u << 20));      // 2 MiB [4][4096][64] bf16
  short* xds   = (short*)(ws + (10u << 20));     // 2 MiB [4][4096][64] bf16

  k1_conv192<<<dim3(256, 4), 256, 0, stream>>>(x1, x2, xw0, xb0, dout, xds);
  k2_small<<<dim3(64, 4), 256, 0, stream>>>(xds, event, xw1, xb1, ew0, eb0,
                                            ew1, eb1, qw, qb, kw, kb, vw, vb,
                                            q_pm, k_pm, v_cm, ef_cm);
  k3_attn<<<dim3(64, 4), 256, 0, stream>>>(q_pm, k_pm, v_cm, O_pm);
  k4_final<<<16384, 256, 0, stream>>>(O_pm, ef_cm, gamma, dout);
}

// Round 3
// 421.112 us; speedup vs baseline: 1.3599x; 1.1433x over previous
//
#include <hip/hip_runtime.h>

typedef __attribute__((ext_vector_type(8))) short bf16x8;
typedef __attribute__((ext_vector_type(4))) float f32x4;

// pack two fp32 -> two bf16 (round-half-up) in one v_perm_b32
__device__ __forceinline__ unsigned pk2(float f0, float f1) {
  return __builtin_amdgcn_perm(__float_as_uint(f1) + 0x8000u,
                               __float_as_uint(f0) + 0x8000u, 0x07060302u);
}
__device__ __forceinline__ short f2bf_s(float f) {
  return (short)((__float_as_uint(f) + 0x8000u) >> 16);
}
__device__ __forceinline__ float bf2f(short s) {
  return __uint_as_float(((unsigned)(unsigned short)s) << 16);
}

// ---------------------------------------------------------------------------
// K1: full-res conv 192->64 + bias + relu; also emits compact down4 copy
// xds[b][n][64] bf16 (n = (h/4)*64 + w/4).
// ---------------------------------------------------------------------------
__global__ __launch_bounds__(256, 3) void k1_conv192(
    const float* __restrict__ x1, const float* __restrict__ x2,
    const float* __restrict__ w0, const float* __restrict__ b0,
    float* __restrict__ xout, short* __restrict__ xds)
{
  const int b    = blockIdx.y;
  const int wv   = threadIdx.x >> 6;
  const int lane = threadIdx.x & 63;
  const int quad = lane >> 4;
  const int l16  = lane & 15;
  const int n0   = blockIdx.x * 256 + wv * 64;

  f32x4 acc[4][4];
  #pragma unroll
  for (int mt = 0; mt < 4; ++mt)
    #pragma unroll
    for (int nt = 0; nt < 4; ++nt)
      acc[mt][nt] = (f32x4){0.f, 0.f, 0.f, 0.f};

  #pragma unroll
  for (int kc = 0; kc < 6; ++kc) {
    bf16x8 af[4];
    #pragma unroll
    for (int mt = 0; mt < 4; ++mt) {
      const float* wrow = w0 + (mt * 16 + l16) * 192 + kc * 32 + quad * 8;
      float4 wa = *(const float4*)wrow;
      float4 wb = *(const float4*)(wrow + 4);
      union { unsigned i[4]; bf16x8 v; } u;
      u.i[0] = pk2(wa.x, wa.y); u.i[1] = pk2(wa.z, wa.w);
      u.i[2] = pk2(wb.x, wb.y); u.i[3] = pk2(wb.z, wb.w);
      af[mt] = u.v;
    }
    const float* src = (kc < 4)
        ? (x1 + ((long)b * 128 + kc * 32) * 65536)
        : (x2 + ((long)b * 64 + (kc - 4) * 32) * 65536);
    const float* s8 = src + (long)(quad * 8) * 65536;
    bf16x8 bfv[4];
    #pragma unroll
    for (int nt = 0; nt < 4; ++nt) {
      const int p = n0 + nt * 16 + l16;
      float e[8];
      #pragma unroll
      for (int j = 0; j < 8; ++j) e[j] = s8[(long)j * 65536 + p];
      union { unsigned i[4]; bf16x8 v; } u;
      #pragma unroll
      for (int j = 0; j < 4; ++j) u.i[j] = pk2(e[2 * j], e[2 * j + 1]);
      bfv[nt] = u.v;
    }
    #pragma unroll
    for (int mt = 0; mt < 4; ++mt)
      #pragma unroll
      for (int nt = 0; nt < 4; ++nt)
        acc[mt][nt] = __builtin_amdgcn_mfma_f32_16x16x32_bf16(
            af[mt], bfv[nt], acc[mt][nt], 0, 0, 0);
  }

  #pragma unroll
  for (int mt = 0; mt < 4; ++mt) {
    const float4 bb = *(const float4*)(b0 + mt * 16 + quad * 4);
    #pragma unroll
    for (int r = 0; r < 4; ++r) {
      const int o = mt * 16 + quad * 4 + r;
      const float bias = (r == 0) ? bb.x : (r == 1) ? bb.y : (r == 2) ? bb.z : bb.w;
      float* orow = xout + ((long)b * 64 + o) * 65536;
      #pragma unroll
      for (int nt = 0; nt < 4; ++nt)
        orow[n0 + nt * 16 + l16] = fmaxf(acc[mt][nt][r] + bias, 0.f);
    }
  }
  if (((blockIdx.x & 3) == 0) && ((l16 & 3) == 0)) {
    const int nbase = (blockIdx.x >> 2) * 64 + wv * 16 + (l16 >> 2);
    #pragma unroll
    for (int mt = 0; mt < 4; ++mt) {
      const float4 bb = *(const float4*)(b0 + mt * 16 + quad * 4);
      #pragma unroll
      for (int nt = 0; nt < 4; ++nt) {
        const float v0 = fmaxf(acc[mt][nt][0] + bb.x, 0.f);
        const float v1 = fmaxf(acc[mt][nt][1] + bb.y, 0.f);
        const float v2 = fmaxf(acc[mt][nt][2] + bb.z, 0.f);
        const float v3 = fmaxf(acc[mt][nt][3] + bb.w, 0.f);
        union { unsigned i[2]; unsigned long long q; } u;
        u.i[0] = pk2(v0, v1); u.i[1] = pk2(v2, v3);
        const int n = nbase + nt * 4;
        *(unsigned long long*)(xds + ((long)b * 4096 + n) * 64 + mt * 16 + quad * 4) = u.q;
      }
    }
  }
}

// ---------------------------------------------------------------------------
// K2: down4-res convs as chained 64x64x64 MFMA GEMMs through LDS (unchanged)
// ---------------------------------------------------------------------------
__device__ __forceinline__ void loadw_frag(const float* __restrict__ w,
                                           int row, int quad, bf16x8 wf[2]) {
  #pragma unroll
  for (int kc = 0; kc < 2; ++kc) {
    const float* p = w + row * 64 + kc * 32 + quad * 8;
    float4 a = *(const float4*)p;
    float4 c = *(const float4*)(p + 4);
    union { unsigned i[4]; bf16x8 v; } u;
    u.i[0] = pk2(a.x, a.y); u.i[1] = pk2(a.z, a.w);
    u.i[2] = pk2(c.x, c.y); u.i[3] = pk2(c.z, c.w);
    wf[kc] = u.v;
  }
}

__device__ __forceinline__ void conv_mfma(const short (*src)[72], short (*dst)[72],
                                          const bf16x8* wf,
                                          const float* __restrict__ bias,
                                          int ch0, int l16, int quad) {
  const float4 bv4 = *(const float4*)(bias + ch0);
  #pragma unroll
  for (int nt = 0; nt < 4; ++nt) {
    f32x4 acc = (f32x4){0.f, 0.f, 0.f, 0.f};
    #pragma unroll
    for (int kc = 0; kc < 2; ++kc) {
      bf16x8 bv = *(const bf16x8*)&src[nt * 16 + l16][kc * 32 + quad * 8];
      acc = __builtin_amdgcn_mfma_f32_16x16x32_bf16(wf[kc], bv, acc, 0, 0, 0);
    }
    const float v0 = fmaxf(acc[0] + bv4.x, 0.f);
    const float v1 = fmaxf(acc[1] + bv4.y, 0.f);
    const float v2 = fmaxf(acc[2] + bv4.z, 0.f);
    const float v3 = fmaxf(acc[3] + bv4.w, 0.f);
    union { unsigned i[2]; unsigned long long q; } u;
    u.i[0] = pk2(v0, v1); u.i[1] = pk2(v2, v3);
    *(unsigned long long*)&dst[nt * 16 + l16][ch0] = u.q;
  }
}

__global__ __launch_bounds__(256) void k2_small(
    const short* __restrict__ xds, const float* __restrict__ event,
    const float* __restrict__ xw1, const float* __restrict__ xb1,
    const float* __restrict__ ew0, const float* __restrict__ eb0,
    const float* __restrict__ ew1, const float* __restrict__ eb1,
    const float* __restrict__ qw, const float* __restrict__ qb,
    const float* __restrict__ kw, const float* __restrict__ kb,
    const float* __restrict__ vw, const float* __restrict__ vb,
    short* __restrict__ q_pm, short* __restrict__ k_pm,
    short* __restrict__ v_cm, short* __restrict__ ef_cm)
{
  __shared__ short A[64][72], Bb[64][72], Cb[64][72];
  const int b    = blockIdx.y;
  const int h4   = blockIdx.x;
  const int t    = threadIdx.x;
  const int lane = t & 63;
  const int g    = t >> 6;
  const int quad = lane >> 4;
  const int l16  = lane & 15;
  const int row  = g * 16 + l16;
  const int ch0  = g * 16 + quad * 4;

  bf16x8 wfx1[2], wfq[2], wfv[2], wfe0[2], wfe1[2], wfk[2];
  loadw_frag(xw1, row, quad, wfx1);
  loadw_frag(qw,  row, quad, wfq);
  loadw_frag(vw,  row, quad, wfv);
  loadw_frag(ew0, row, quad, wfe0);
  loadw_frag(ew1, row, quad, wfe1);
  loadw_frag(kw,  row, quad, wfk);

  const int px  = t >> 2;
  const int seg = t & 3;
  {
    const short* s = xds + ((long)b * 4096 + h4 * 64 + px) * 64 + seg * 16;
    *(bf16x8*)&A[px][seg * 16]     = *(const bf16x8*)s;
    *(bf16x8*)&A[px][seg * 16 + 8] = *(const bf16x8*)(s + 8);
  }
  __syncthreads();
  conv_mfma(A, Bb, wfx1, xb1, ch0, l16, quad);
  __syncthreads();
  conv_mfma(Bb, A,  wfq, qb, ch0, l16, quad);
  conv_mfma(Bb, Cb, wfv, vb, ch0, l16, quad);
  __syncthreads();
  {
    short* qdst = q_pm + ((long)b * 4096 + h4 * 64 + px) * 64 + seg * 16;
    *(bf16x8*)qdst       = *(const bf16x8*)&A[px][seg * 16];
    *(bf16x8*)(qdst + 8) = *(const bf16x8*)&A[px][seg * 16 + 8];
    union { short s[16]; int4 q2[2]; } vv;
    #pragma unroll
    for (int i = 0; i < 16; ++i) vv.s[i] = Cb[seg * 16 + i][px];
    int4* vdst = (int4*)(v_cm + ((long)b * 64 + px) * 4096 + h4 * 64 + seg * 16);
    vdst[0] = vv.q2[0]; vdst[1] = vv.q2[1];
    const int px2 = t & 63, cg = t >> 6;
    const float* ev = event + (long)b * 64 * 65536 + (long)h4 * 1024 + px2 * 4;
    #pragma unroll
    for (int r = 0; r < 16; r += 2) {
      const float e0v = ev[(long)(cg * 16 + r) * 65536];
      const float e1v = ev[(long)(cg * 16 + r + 1) * 65536];
      *(unsigned*)&Bb[px2][cg * 16 + r] = pk2(e0v, e1v);
    }
  }
  __syncthreads();
  conv_mfma(Bb, A,  wfe0, eb0, ch0, l16, quad);
  __syncthreads();
  conv_mfma(A,  Cb, wfe1, eb1, ch0, l16, quad);
  __syncthreads();
  conv_mfma(Cb, Bb, wfk, kb, ch0, l16, quad);
  {
    union { short s[16]; int4 q2[2]; } vv;
    #pragma unroll
    for (int i = 0; i < 16; ++i) vv.s[i] = Cb[seg * 16 + i][px];
    int4* edst = (int4*)(ef_cm + ((long)b * 64 + px) * 4096 + h4 * 64 + seg * 16);
    edst[0] = vv.q2[0]; edst[1] = vv.q2[1];
  }
  __syncthreads();
  {
    short* kdst = k_pm + ((long)b * 4096 + h4 * 64 + px) * 64 + seg * 16;
    *(bf16x8*)kdst       = *(const bf16x8*)&Bb[px][seg * 16];
    *(bf16x8*)(kdst + 8) = *(const bf16x8*)&Bb[px][seg * 16 + 8];
  }
}

// ---------------------------------------------------------------------------
// K3: flash attention, transposed orientation, split-K by 4.
// St = K.Q^T (A=K-frag, B=Q-frag); per-lane q column => 2-round shuffles.
// Ot = V.P^T (A=V-frag, B=P-frag via frag-order LDS, conflict-free).
// K/V staged in fragment order, double-buffered, 1 barrier/tile.
// Outputs: Opart[ks][b][ch][q] bf16 (unnormalized), ml[ks][b][q] = (m,l).
// ---------------------------------------------------------------------------
__global__ __launch_bounds__(256, 4) void k3_attn(
    const short* __restrict__ q_pm, const short* __restrict__ k_pm,
    const short* __restrict__ v_cm, short* __restrict__ Opart,
    float* __restrict__ ml)
{
  __shared__ short Kf[2][4096];
  __shared__ short Vf[2][4096];
  __shared__ short Pf[4][2][512];
  const int b    = blockIdx.y;
  const int ks   = blockIdx.z;
  const int q0   = blockIdx.x * 64;
  const int t    = threadIdx.x;
  const int wv   = __builtin_amdgcn_readfirstlane(t >> 6);
  const int lane = t & 63;
  const int quad = lane >> 4;
  const int l16  = lane & 15;

  // Q B-frags: lane l16 = q column
  bf16x8 qf[2];
  {
    const short* qp = q_pm + ((long)b * 4096 + q0 + wv * 16 + l16) * 64 + quad * 8;
    qf[0] = *(const bf16x8*)qp;
    qf[1] = *(const bf16x8*)(qp + 32);
  }

  // staging geometry: thread covers (row=t>>2, ch/key chunk seg*16..+15)
  const int srow  = t >> 2;
  const int seg   = t & 3;
  const int doff0 = (((seg >> 1) * 4 + (srow >> 4)) * 64 +
                     ((seg & 1) * 2) * 16 + (srow & 15)) * 8;
  const short* kbase = k_pm + (long)b * 4096 * 64;
  const short* vbase = v_cm + (long)b * 64 * 4096;
  const int kt0 = ks * 16;

  bf16x8 krg[2], vrg[2];
  {
    const short* s = kbase + (long)(kt0 * 64 + srow) * 64 + seg * 16;
    krg[0] = *(const bf16x8*)s; krg[1] = *(const bf16x8*)(s + 8);
    const short* v = vbase + (long)srow * 4096 + kt0 * 64 + seg * 16;
    vrg[0] = *(const bf16x8*)v; vrg[1] = *(const bf16x8*)(v + 8);
  }
  *(bf16x8*)&Kf[0][doff0]       = krg[0];
  *(bf16x8*)&Kf[0][doff0 + 128] = krg[1];
  *(bf16x8*)&Vf[0][doff0]       = vrg[0];
  *(bf16x8*)&Vf[0][doff0 + 128] = vrg[1];
  __syncthreads();

  f32x4 oacc[4];
  #pragma unroll
  for (int f = 0; f < 4; ++f) oacc[f] = (f32x4){0, 0, 0, 0};
  float run_m = -1e30f, run_l = 0.f;

  for (int kt = 0; kt < 16; ++kt) {
    if (kt < 15) {
      const int k0 = (kt0 + kt + 1) * 64;
      const short* s = kbase + (long)(k0 + srow) * 64 + seg * 16;
      krg[0] = *(const bf16x8*)s; krg[1] = *(const bf16x8*)(s + 8);
      const short* v = vbase + (long)srow * 4096 + k0 + seg * 16;
      vrg[0] = *(const bf16x8*)v; vrg[1] = *(const bf16x8*)(v + 8);
    }
    const int buf = kt & 1;

    // St[key][q]: rows key=f*16+quad*4+r, col q=l16
    f32x4 st[4];
    #pragma unroll
    for (int f = 0; f < 4; ++f) st[f] = (f32x4){0, 0, 0, 0};
    #pragma unroll
    for (int kc = 0; kc < 2; ++kc)
      #pragma unroll
      for (int f = 0; f < 4; ++f) {
        bf16x8 ka = *(const bf16x8*)&Kf[buf][((kc * 4 + f) * 64 + lane) * 8];
        st[f] = __builtin_amdgcn_mfma_f32_16x16x32_bf16(ka, qf[kc], st[f], 0, 0, 0);
      }

    // online softmax: each lane owns one q; reduce over 16 in-lane + 2 shfl
    float tm = st[0][0];
    #pragma unroll
    for (int f = 0; f < 4; ++f)
      #pragma unroll
      for (int r = 0; r < 4; ++r) tm = fmaxf(tm, st[f][r]);
    tm = fmaxf(tm, __shfl_xor(tm, 16));
    tm = fmaxf(tm, __shfl_xor(tm, 32));
    const float nm = fmaxf(run_m, tm);
    const float al = __expf(run_m - nm);
    run_m = nm;
    float pf[4][4], ts = 0.f;
    #pragma unroll
    for (int f = 0; f < 4; ++f)
      #pragma unroll
      for (int r = 0; r < 4; ++r) {
        pf[f][r] = __expf(st[f][r] - nm);
        ts += pf[f][r];
      }
    ts += __shfl_xor(ts, 16);
    ts += __shfl_xor(ts, 32);
    run_l = run_l * al + ts;
    #pragma unroll
    for (int f = 0; f < 4; ++f)
      #pragma unroll
      for (int r = 0; r < 4; ++r) oacc[f][r] *= al;

    // P^T -> B-frag order LDS: key=f*16+quad*4+r, q=l16
    #pragma unroll
    for (int f = 0; f < 4; ++f) {
      union { unsigned i[2]; unsigned long long q; } u;
      u.i[0] = pk2(pf[f][0], pf[f][1]);
      u.i[1] = pk2(pf[f][2], pf[f][3]);
      const int qd = (f & 1) * 2 + (quad >> 1);
      *(unsigned long long*)&Pf[wv][f >> 1][(qd * 16 + l16) * 8 + (quad & 1) * 4] = u.q;
    }
    // Ot[ch][q] += V . P^T
    #pragma unroll
    for (int kc = 0; kc < 2; ++kc) {
      bf16x8 pb = *(const bf16x8*)&Pf[wv][kc][lane * 8];
      #pragma unroll
      for (int f = 0; f < 4; ++f) {
        bf16x8 va = *(const bf16x8*)&Vf[buf][((kc * 4 + f) * 64 + lane) * 8];
        oacc[f] = __builtin_amdgcn_mfma_f32_16x16x32_bf16(va, pb, oacc[f], 0, 0, 0);
      }
    }

    if (kt < 15) {
      const int nb = buf ^ 1;
      *(bf16x8*)&Kf[nb][doff0]       = krg[0];
      *(bf16x8*)&Kf[nb][doff0 + 128] = krg[1];
      *(bf16x8*)&Vf[nb][doff0]       = vrg[0];
      *(bf16x8*)&Vf[nb][doff0 + 128] = vrg[1];
      __syncthreads();
    }
  }

  // epilogue: unnormalized Ot + (m,l)
  const int q = q0 + wv * 16 + l16;
  #pragma unroll
  for (int f = 0; f < 4; ++f)
    #pragma unroll
    for (int r = 0; r < 4; ++r) {
      const int ch = f * 16 + quad * 4 + r;
      Opart[((long)(ks * 4 + b) * 64 + ch) * 4096 + q] = f2bf_s(oacc[f][r]);
    }
  if (quad == 0) {
    float2 v = make_float2(run_m, run_l);
    *(float2*)&ml[((long)(ks * 4 + b) * 4096 + q) * 2] = v;
  }
}

// ---------------------------------------------------------------------------
// K3W: combine weights per (b,q): w_s = exp(m_s-M) / sum_s exp(m_s-M) l_s
// ---------------------------------------------------------------------------
__global__ __launch_bounds__(256) void k3w(const float* __restrict__ ml,
                                           float* __restrict__ wc)
{
  const int idx = blockIdx.x * 256 + threadIdx.x;   // b*4096+q, 16384 total
  const float2* m2 = (const float2*)ml;
  float2 s0 = m2[0 * 16384 + idx];
  float2 s1 = m2[1 * 16384 + idx];
  float2 s2 = m2[2 * 16384 + idx];
  float2 s3 = m2[3 * 16384 + idx];
  const float M = fmaxf(fmaxf(s0.x, s1.x), fmaxf(s2.x, s3.x));
  const float e0 = __expf(s0.x - M), e1 = __expf(s1.x - M);
  const float e2 = __expf(s2.x - M), e3 = __expf(s3.x - M);
  const float inv = 1.f / (e0 * s0.y + e1 * s1.y + e2 * s2.y + e3 * s3.y);
  *(float4*)&wc[idx * 4] = make_float4(e0 * inv, e1 * inv, e2 * inv, e3 * inv);
}

// ---------------------------------------------------------------------------
// K4: out = x + THITA*gamma*up4(combine(Opart));  ef_up = up4(ef).
// ---------------------------------------------------------------------------
__global__ __launch_bounds__(256) void k4_final(
    const short* __restrict__ Opart, const float* __restrict__ wc,
    const short* __restrict__ ef_cm, const float* __restrict__ gamma,
    float* __restrict__ dout)
{
  const long idx = (long)blockIdx.x * 256 + threadIdx.x;
  const long e4 = idx * 4;
  const int hw = (int)(e4 & 65535);
  const int bc = (int)(e4 >> 16);
  const int h = hw >> 8, w0 = hw & 255;
  const int n = (h >> 2) * 64 + (w0 >> 2);
  const int b = bc >> 6, c = bc & 63;
  const float s = 1e-4f * gamma[0];
  const float4 w4 = *(const float4*)&wc[((long)b * 4096 + n) * 4];
  const long obase = ((long)b * 64 + c) * 4096 + n;
  float ov = w4.x * bf2f(Opart[obase]) +
             w4.y * bf2f(Opart[obase + (long)1 * 4 * 64 * 4096]) +
             w4.z * bf2f(Opart[obase + (long)2 * 4 * 64 * 4096]) +
             w4.w * bf2f(Opart[obase + (long)3 * 4 * 64 * 4096]);
  ov *= s;
  float4 xv = *(float4*)(dout + e4);
  xv.x += ov; xv.y += ov; xv.z += ov; xv.w += ov;
  *(float4*)(dout + e4) = xv;
  const float ef = bf2f(ef_cm[(long)bc * 4096 + n]);
  *(float4*)(dout + 16777216 + e4) = make_float4(ef, ef, ef, ef);
}

extern "C" void kernel_launch(void* const* d_in, const int* in_sizes, int n_in,
                              void* d_out, int out_size, void* d_ws, size_t ws_size,
                              hipStream_t stream)
{
  const float* x1    = (const float*)d_in[0];
  const float* x2    = (const float*)d_in[1];
  const float* event = (const float*)d_in[2];
  const float* xw0   = (const float*)d_in[3];
  const float* xb0   = (const float*)d_in[4];
  const float* xw1   = (const float*)d_in[5];
  const float* xb1   = (const float*)d_in[6];
  const float* ew0   = (const float*)d_in[7];
  const float* eb0   = (const float*)d_in[8];
  const float* ew1   = (const float*)d_in[9];
  const float* eb1   = (const float*)d_in[10];
  const float* qw    = (const float*)d_in[11];
  const float* qb    = (const float*)d_in[12];
  const float* kw    = (const float*)d_in[13];
  const float* kb    = (const float*)d_in[14];
  const float* vw    = (const float*)d_in[15];
  const float* vb    = (const float*)d_in[16];
  const float* gamma = (const float*)d_in[17];
  float* dout = (float*)d_out;

  char* ws = (char*)d_ws;
  short* q_pm  = (short*)(ws);                   // 2 MiB [4][4096][64] bf16
  short* k_pm  = (short*)(ws + (2u << 20));      // 2 MiB [4][4096][64] bf16
  short* v_cm  = (short*)(ws + (4u << 20));      // 2 MiB [4][64][4096] bf16
  short* ef_cm = (short*)(ws + (6u << 20));      // 2 MiB [4][64][4096] bf16
  short* xds   = (short*)(ws + (8u << 20));      // 2 MiB [4][4096][64] bf16
  short* Opart = (short*)(ws + (10u << 20));     // 8 MiB [4][4][64][4096] bf16
  float* ml    = (float*)(ws + (18u << 20));     // 512 KiB [4][4][4096][2] f32
  float* wc    = (float*)(ws + (18u << 20) + (512u << 10)); // 256 KiB

  k1_conv192<<<dim3(256, 4), 256, 0, stream>>>(x1, x2, xw0, xb0, dout, xds);
  k2_small<<<dim3(64, 4), 256, 0, stream>>>(xds, event, xw1, xb1, ew0, eb0,
                                            ew1, eb1, qw, qb, kw, kb, vw, vb,
                                            q_pm, k_pm, v_cm, ef_cm);
  k3_attn<<<dim3(64, 4, 4), 256, 0, stream>>>(q_pm, k_pm, v_cm, Opart, ml);
  k3w<<<64, 256, 0, stream>>>(ml, wc);
  k4_final<<<16384, 256, 0, stream>>>(Opart, wc, ef_cm, gamma, dout);
}